// Round 4
// baseline (1611.479 us; speedup 1.0000x reference)
//
#include <hip/hip_runtime.h>
#include <hip/hip_bf16.h>

// Problem constants (B,T,H,D,M) = (2, 2048, 8, 64, 64), fp32 in/out.
#define BB 2
#define TT 2048
#define HH 8
#define DD 64
#define CC 256            // chunks over T
#define TC (TT / CC)      // 8 timesteps per chunk
#define STRIDE (HH * DD)  // 512 floats between consecutive timesteps
#define NBH (BB * HH)     // 16
#define NCHUNK (NBH * CC) // 4096 waves / tickets

// ws layout (4-byte units):
//   [0]              ticket counter (zeroed each call)
//   [64 .. 64+4096)  flags: 0=not ready, 1=partial, 2=inclusive prefix (zeroed)
//   [8192 ..)        sums  : NCHUNK*DD floats (chunk sums)
//   [8192+NCHUNK*DD) prefs : NCHUNK*DD floats (inclusive prefixes)
#define WS_FLAGS_OFF 64
#define WS_SUMS_OFF  8192
#define WS_CTRL_BYTES ((64 + NCHUNK) * 4)

__device__ __forceinline__ float feat(float x) {
    // elu(x) + 1 = x+1 (x>0) else exp(x)
    return x > 0.f ? x + 1.f : __expf(x);
}

__global__ void __launch_bounds__(64)
linattn_onepass(const float* __restrict__ q, const float* __restrict__ k,
                const float* __restrict__ v, float* __restrict__ out,
                unsigned* __restrict__ ticket, unsigned* __restrict__ flags,
                float* __restrict__ sums, float* __restrict__ prefs) {
    const int lane = threadIdx.x;

    // Dynamic ticket: guarantees that within each (b,h), chunk c starts only
    // after all chunks < c have started -> lookback spin cannot deadlock.
    unsigned t;
    if (lane == 0) t = atomicAdd(ticket, 1u);
    t = (unsigned)__shfl((int)t, 0, 64);
    const int bh = t & (NBH - 1);   // round-robin (b,h) across consecutive tickets
    const int c  = t >> 4;          // increases with ticket within each (b,h)
    const int h  = bh & (HH - 1);
    const int b  = bh >> 3;

    size_t base = (((size_t)b * TT + c * TC) * HH + h) * DD + lane;

    // Issue all chunk loads up front (independent; one latency exposure).
    float kf[TC], qf[TC], vv[TC];
    #pragma unroll
    for (int i = 0; i < TC; ++i) kf[i] = k[base + (size_t)i * STRIDE];
    #pragma unroll
    for (int i = 0; i < TC; ++i) qf[i] = q[base + (size_t)i * STRIDE];
    #pragma unroll
    for (int i = 0; i < TC; ++i) vv[i] = v[base + (size_t)i * STRIDE];

    // Feature map + this chunk's sum of kf per lane (d).
    #pragma unroll
    for (int i = 0; i < TC; ++i) { kf[i] = feat(kf[i]); qf[i] = feat(qf[i]); }
    float csum = 0.f;
    #pragma unroll
    for (int i = 0; i < TC; ++i) csum += kf[i];

    const int fidx = bh * CC + c;
    const int didx = fidx * DD + lane;

    float carry = 0.f;
    if (c == 0) {
        // Inclusive prefix == chunk sum; publish directly as PREFIX.
        __hip_atomic_store(&prefs[didx], csum, __ATOMIC_RELAXED, __HIP_MEMORY_SCOPE_AGENT);
        __threadfence();
        if (lane == 0)
            __hip_atomic_store(&flags[fidx], 2u, __ATOMIC_RELEASE, __HIP_MEMORY_SCOPE_AGENT);
    } else {
        // Publish partial first so successors can make progress.
        __hip_atomic_store(&sums[didx], csum, __ATOMIC_RELAXED, __HIP_MEMORY_SCOPE_AGENT);
        __threadfence();
        if (lane == 0)
            __hip_atomic_store(&flags[fidx], 1u, __ATOMIC_RELEASE, __HIP_MEMORY_SCOPE_AGENT);

        // Decoupled lookback.
        int cp = c - 1;
        while (true) {
            const int pf = bh * CC + cp;
            unsigned st;
            if (lane == 0) {
                st = __hip_atomic_load(&flags[pf], __ATOMIC_ACQUIRE, __HIP_MEMORY_SCOPE_AGENT);
                while (st == 0u) {
                    __builtin_amdgcn_s_sleep(2);
                    st = __hip_atomic_load(&flags[pf], __ATOMIC_ACQUIRE, __HIP_MEMORY_SCOPE_AGENT);
                }
            }
            st = (unsigned)__shfl((int)st, 0, 64);
            // Per-lane acquire on the flag (flag is monotone; establishes ordering
            // for this lane's subsequent data load).
            (void)__hip_atomic_load(&flags[pf], __ATOMIC_ACQUIRE, __HIP_MEMORY_SCOPE_AGENT);
            const int pd = pf * DD + lane;
            if (st == 2u) {
                carry += __hip_atomic_load(&prefs[pd], __ATOMIC_RELAXED, __HIP_MEMORY_SCOPE_AGENT);
                break;
            } else {
                carry += __hip_atomic_load(&sums[pd], __ATOMIC_RELAXED, __HIP_MEMORY_SCOPE_AGENT);
                --cp;
                if (cp < 0) break;
            }
        }

        // Publish inclusive prefix (upgrades flag 1 -> 2).
        __hip_atomic_store(&prefs[didx], carry + csum, __ATOMIC_RELAXED, __HIP_MEMORY_SCOPE_AGENT);
        __threadfence();
        if (lane == 0)
            __hip_atomic_store(&flags[fidx], 2u, __ATOMIC_RELEASE, __HIP_MEMORY_SCOPE_AGENT);
    }

    // ---- compute epilogue (identical math to the verified 3-kernel version) ----

    // Inclusive time-cumsum of kf per lane (d), seeded with exclusive carry.
    float run[TC];
    run[0] = carry + kf[0];
    #pragma unroll
    for (int i = 1; i < TC; ++i) run[i] = run[i - 1] + kf[i];

    // Batched inclusive lane-prefix scans of kf over d: 6 steps × TC indep shfls.
    #pragma unroll
    for (int o = 1; o < 64; o <<= 1) {
        float u[TC];
        #pragma unroll
        for (int i = 0; i < TC; ++i) u[i] = __shfl_up(kf[i], o, 64);
        #pragma unroll
        for (int i = 0; i < TC; ++i) if (lane >= o) kf[i] += u[i];
    }
    // kf[i] now holds inclusive prefix over d of feat(k) at timestep i.

    // Batched butterfly reductions: a -> s2 (denominator), s -> s1 (numerator).
    float a[TC], s[TC];
    #pragma unroll
    for (int i = 0; i < TC; ++i) { a[i] = qf[i] * run[i]; s[i] = qf[i] * kf[i]; }
    #pragma unroll
    for (int o = 32; o >= 1; o >>= 1) {
        #pragma unroll
        for (int i = 0; i < TC; ++i) {
            a[i] += __shfl_xor(a[i], o, 64);
            s[i] += __shfl_xor(s[i], o, 64);
        }
    }

    #pragma unroll
    for (int i = 0; i < TC; ++i)
        out[base + (size_t)i * STRIDE] = vv[i] * (s[i] * __builtin_amdgcn_rcpf(a[i]));
}

extern "C" void kernel_launch(void* const* d_in, const int* in_sizes, int n_in,
                              void* d_out, int out_size, void* d_ws, size_t ws_size,
                              hipStream_t stream) {
    const float* q = (const float*)d_in[0];
    const float* k = (const float*)d_in[1];
    const float* v = (const float*)d_in[2];
    float* out = (float*)d_out;

    unsigned* ticket = (unsigned*)d_ws;
    unsigned* flags  = ticket + WS_FLAGS_OFF;
    float*    sums   = (float*)d_ws + WS_SUMS_OFF;
    float*    prefs  = sums + (size_t)NCHUNK * DD;

    // Zero ticket + flags (16.6 KB) every call; sums/prefs are flag-gated.
    hipMemsetAsync(d_ws, 0, WS_CTRL_BYTES, stream);

    linattn_onepass<<<NCHUNK, 64, 0, stream>>>(q, k, v, out, ticket, flags, sums, prefs);
}

// Round 5
// 80.336 us; speedup vs baseline: 20.0593x; 20.0593x over previous
//
#include <hip/hip_runtime.h>
#include <hip/hip_bf16.h>

// Problem constants (B,T,H,D,M) = (2, 2048, 8, 64, 64), fp32 in/out.
#define BB 2
#define TT 2048
#define HH 8
#define DD 64
#define CC 256           // chunks over T
#define TC (TT / CC)     // 8 timesteps per chunk (= 4 segs x 2 iters)
#define STRIDE (HH * DD) // 512 floats between consecutive timesteps
#define NBH (BB * HH)    // 16
#define PW (CC / 16)     // 16 chunks per wave in prefix_kernel

__device__ __forceinline__ float feat(float x) {
    // elu(x) + 1 = x+1 (x>0) else exp(x)
    return x > 0.f ? x + 1.f : __expf(x);
}

// Lane map for K1/K3: g = lane&15 -> d-group (d = 4g..4g+3), seg = lane>>4 ->
// timestep within group-of-4. One wave float4-load = 4 timesteps x 64 d = 1 KB.

// Kernel 1: per (b,h,c) chunk sums of feat(k) over time. wave per chunk.
__global__ void __launch_bounds__(64)
chunk_sums_kernel(const float* __restrict__ k, float* __restrict__ ws) {
    const int idx  = blockIdx.x;              // (b*H + h)*CC + c
    const int c    = idx & (CC - 1);
    const int h    = (idx >> 8) & (HH - 1);
    const int b    = idx >> 11;
    const int lane = threadIdx.x;
    const int g    = lane & 15;
    const int seg  = lane >> 4;

    const size_t off0 = (((size_t)b * TT + c * TC + seg) * HH + h) * DD + g * 4;
    const float4 k0 = *(const float4*)(k + off0);
    const float4 k1 = *(const float4*)(k + off0 + (size_t)4 * STRIDE);

    float4 s;
    s.x = feat(k0.x) + feat(k1.x);
    s.y = feat(k0.y) + feat(k1.y);
    s.z = feat(k0.z) + feat(k1.z);
    s.w = feat(k0.w) + feat(k1.w);

    // reduce over the 4 segments (lanes ^16, ^32)
    s.x += __shfl_xor(s.x, 16, 64); s.y += __shfl_xor(s.y, 16, 64);
    s.z += __shfl_xor(s.z, 16, 64); s.w += __shfl_xor(s.w, 16, 64);
    s.x += __shfl_xor(s.x, 32, 64); s.y += __shfl_xor(s.y, 32, 64);
    s.z += __shfl_xor(s.z, 32, 64); s.w += __shfl_xor(s.w, 32, 64);

    if (seg == 0)
        *(float4*)(ws + (size_t)idx * DD + g * 4) = s;
}

// Kernel 2 (verified round-3): in-place ws chunk sums -> EXCLUSIVE prefix over c.
__global__ void __launch_bounds__(1024)
prefix_kernel(float* __restrict__ ws) {
    const int bh   = blockIdx.x;              // 0..15
    const int lane = threadIdx.x & 63;        // d
    const int w    = threadIdx.x >> 6;        // wave id 0..15

    size_t base = ((size_t)bh * CC + w * PW) * DD + lane;

    float val[PW];
    #pragma unroll
    for (int i = 0; i < PW; ++i) val[i] = ws[base + (size_t)i * DD];

    float run = 0.f, excl[PW];
    #pragma unroll
    for (int i = 0; i < PW; ++i) { excl[i] = run; run += val[i]; }

    __shared__ float tot[16][DD];
    tot[w][lane] = run;
    __syncthreads();

    float carry = 0.f;
    for (int w2 = 0; w2 < w; ++w2) carry += tot[w2][lane];

    #pragma unroll
    for (int i = 0; i < PW; ++i) ws[base + (size_t)i * DD] = excl[i] + carry;
}

// Kernel 3: main. One wave per (b,h,c) chunk, float4 lane map.
__global__ void __launch_bounds__(64)
linattn_kernel(const float* __restrict__ q, const float* __restrict__ k,
               const float* __restrict__ v, const float* __restrict__ ws,
               float* __restrict__ out) {
    const int idx  = blockIdx.x;
    const int c    = idx & (CC - 1);
    const int h    = (idx >> 8) & (HH - 1);
    const int b    = idx >> 11;
    const int lane = threadIdx.x;
    const int g    = lane & 15;
    const int seg  = lane >> 4;

    // lane's timesteps: t0 = c*TC + seg (iter 0), t0+4 (iter 1); d = 4g..4g+3
    const size_t off0 = (((size_t)b * TT + c * TC + seg) * HH + h) * DD + g * 4;
    const size_t off1 = off0 + (size_t)4 * STRIDE;

    float4 kf0 = *(const float4*)(k + off0);
    float4 kf1 = *(const float4*)(k + off1);
    float4 qf0 = *(const float4*)(q + off0);
    float4 qf1 = *(const float4*)(q + off1);
    const float4 vv0 = *(const float4*)(v + off0);
    const float4 vv1 = *(const float4*)(v + off1);
    const float4 carry = *(const float4*)(ws + (size_t)idx * DD + g * 4); // excl prefix per d

    kf0.x = feat(kf0.x); kf0.y = feat(kf0.y); kf0.z = feat(kf0.z); kf0.w = feat(kf0.w);
    kf1.x = feat(kf1.x); kf1.y = feat(kf1.y); kf1.z = feat(kf1.z); kf1.w = feat(kf1.w);
    qf0.x = feat(qf0.x); qf0.y = feat(qf0.y); qf0.z = feat(qf0.z); qf0.w = feat(qf0.w);
    qf1.x = feat(qf1.x); qf1.y = feat(qf1.y); qf1.z = feat(qf1.z); qf1.w = feat(qf1.w);

    // ---- time cumsum per d: seg-inclusive scans of kf0/kf1 (Hillis-Steele o=16,32)
    float4 i0 = kf0, i1 = kf1;
    {
        float u;
        u = __shfl_up(i0.x, 16, 64); if (seg >= 1) i0.x += u;
        u = __shfl_up(i0.y, 16, 64); if (seg >= 1) i0.y += u;
        u = __shfl_up(i0.z, 16, 64); if (seg >= 1) i0.z += u;
        u = __shfl_up(i0.w, 16, 64); if (seg >= 1) i0.w += u;
        u = __shfl_up(i1.x, 16, 64); if (seg >= 1) i1.x += u;
        u = __shfl_up(i1.y, 16, 64); if (seg >= 1) i1.y += u;
        u = __shfl_up(i1.z, 16, 64); if (seg >= 1) i1.z += u;
        u = __shfl_up(i1.w, 16, 64); if (seg >= 1) i1.w += u;
        u = __shfl_up(i0.x, 32, 64); if (seg >= 2) i0.x += u;
        u = __shfl_up(i0.y, 32, 64); if (seg >= 2) i0.y += u;
        u = __shfl_up(i0.z, 32, 64); if (seg >= 2) i0.z += u;
        u = __shfl_up(i0.w, 32, 64); if (seg >= 2) i0.w += u;
        u = __shfl_up(i1.x, 32, 64); if (seg >= 2) i1.x += u;
        u = __shfl_up(i1.y, 32, 64); if (seg >= 2) i1.y += u;
        u = __shfl_up(i1.z, 32, 64); if (seg >= 2) i1.z += u;
        u = __shfl_up(i1.w, 32, 64); if (seg >= 2) i1.w += u;
    }
    // S0[d] = chunk-first-half total = i0 at seg=3 (lane 48+g), broadcast
    float4 S0;
    S0.x = __shfl(i0.x, 48 + g, 64);
    S0.y = __shfl(i0.y, 48 + g, 64);
    S0.z = __shfl(i0.z, 48 + g, 64);
    S0.w = __shfl(i0.w, 48 + g, 64);

    float4 run0, run1;   // inclusive time-cumsum of feat(k) per d
    run0.x = carry.x + i0.x; run0.y = carry.y + i0.y;
    run0.z = carry.z + i0.z; run0.w = carry.w + i0.w;
    run1.x = carry.x + S0.x + i1.x; run1.y = carry.y + S0.y + i1.y;
    run1.z = carry.z + S0.z + i1.z; run1.w = carry.w + S0.w + i1.w;

    // ---- d-prefix (inclusive over d) per timestep: in-lane prefix + group scan
    float4 p0, p1;
    p0.x = kf0.x; p0.y = p0.x + kf0.y; p0.z = p0.y + kf0.z; p0.w = p0.z + kf0.w;
    p1.x = kf1.x; p1.y = p1.x + kf1.y; p1.z = p1.y + kf1.z; p1.w = p1.z + kf1.w;
    float c0 = p0.w, c1 = p1.w;
    #pragma unroll
    for (int o = 1; o <= 8; o <<= 1) {
        float u0 = __shfl_up(c0, o, 16);
        float u1 = __shfl_up(c1, o, 16);
        if (g >= o) { c0 += u0; c1 += u1; }
    }
    const float e0 = c0 - p0.w;   // exclusive d-prefix entering this lane
    const float e1 = c1 - p1.w;
    float4 pre0, pre1;
    pre0.x = p0.x + e0; pre0.y = p0.y + e0; pre0.z = p0.z + e0; pre0.w = p0.w + e0;
    pre1.x = p1.x + e1; pre1.y = p1.y + e1; pre1.z = p1.z + e1; pre1.w = p1.w + e1;

    // ---- reductions over d: s1 = qf.pre, s2 = qf.run (per timestep = per segment)
    float s1_0 = qf0.x * pre0.x + qf0.y * pre0.y + qf0.z * pre0.z + qf0.w * pre0.w;
    float s2_0 = qf0.x * run0.x + qf0.y * run0.y + qf0.z * run0.z + qf0.w * run0.w;
    float s1_1 = qf1.x * pre1.x + qf1.y * pre1.y + qf1.z * pre1.z + qf1.w * pre1.w;
    float s2_1 = qf1.x * run1.x + qf1.y * run1.y + qf1.z * run1.z + qf1.w * run1.w;
    #pragma unroll
    for (int o = 1; o <= 8; o <<= 1) {
        s1_0 += __shfl_xor(s1_0, o, 64);
        s2_0 += __shfl_xor(s2_0, o, 64);
        s1_1 += __shfl_xor(s1_1, o, 64);
        s2_1 += __shfl_xor(s2_1, o, 64);
    }

    const float r0 = s1_0 / s2_0;
    const float r1 = s1_1 / s2_1;
    float4 o0, o1;
    o0.x = vv0.x * r0; o0.y = vv0.y * r0; o0.z = vv0.z * r0; o0.w = vv0.w * r0;
    o1.x = vv1.x * r1; o1.y = vv1.y * r1; o1.z = vv1.z * r1; o1.w = vv1.w * r1;
    *(float4*)(out + off0) = o0;
    *(float4*)(out + off1) = o1;
}

extern "C" void kernel_launch(void* const* d_in, const int* in_sizes, int n_in,
                              void* d_out, int out_size, void* d_ws, size_t ws_size,
                              hipStream_t stream) {
    const float* q = (const float*)d_in[0];
    const float* k = (const float*)d_in[1];
    const float* v = (const float*)d_in[2];
    float* out = (float*)d_out;
    float* ws  = (float*)d_ws;            // needs B*H*CC*DD*4 = 1 MB

    const int nblk = BB * HH * CC;        // 4096
    chunk_sums_kernel<<<nblk, 64, 0, stream>>>(k, ws);
    prefix_kernel<<<NBH, 1024, 0, stream>>>(ws);
    linattn_kernel<<<nblk, 64, 0, stream>>>(q, k, v, ws, out);
}